// Round 10
// baseline (352.869 us; speedup 1.0000x reference)
//
#include <hip/hip_runtime.h>
#include <cstdint>

typedef _Float16 half8 __attribute__((ext_vector_type(8)));
typedef _Float16 half4v __attribute__((ext_vector_type(4)));
typedef __attribute__((ext_vector_type(4))) float floatx4;
typedef __attribute__((ext_vector_type(2))) float float2v;
typedef unsigned int uint;

#define TSEQ 256
#define TDEC 180
#define NIN  6
#define GROWS 16
#define NBLK (4096 / GROWS)
#define NSL 4     // state buffer depth: h(j) lives in slot (j+1)&3
#define RS0 104   // s0 row stride (halfs): cols 0..63 h0, 64..95 x|0, 96..103 pad
#define RS1 72    // s1 row stride
#define L2E 1.4426950408889634f

__device__ __forceinline__ floatx4 mfma16(half8 a, half8 b, floatx4 c) {
  return __builtin_amdgcn_mfma_f32_16x16x32_f16(a, b, c, 0, 0, 0);
}

__device__ __forceinline__ half8 ldh8(const _Float16* p) { return *(const half8*)p; }

// ---- OPERAND-SWAPPED MFMA passes: gates^T = W_tile . h^T (bit-identical sums;
// C layout (gate row, batch col) -> lane's 4 outputs are 4 consecutive h-cols
// of one batch row -> single ds_write_b64).
#define PASS2_I3(F0, F1, r, z, g, W, QR, QZ, QG) do {                   \
  r = mfma16(W[0][0], F0, QR); z = mfma16(W[1][0], F0, QZ); g = mfma16(W[2][0], F0, QG); \
  r = mfma16(W[0][1], F1, r);  z = mfma16(W[1][1], F1, z);  g = mfma16(W[2][1], F1, g);  \
} while (0)

#define PASS2_A2I1(F0, F1, r, z, g, W, QG) do {                         \
  r = mfma16(W[0][0], F0, r); z = mfma16(W[1][0], F0, z); g = mfma16(W[2][0], F0, QG); \
  r = mfma16(W[0][1], F1, r); z = mfma16(W[1][1], F1, z); g = mfma16(W[2][1], F1, g);  \
} while (0)

// layer0 x-pass: only the first K-half is nonzero (x has 6 features) -> 1-D W.
#define PASS1_I1(F0, r, z, g, W3, QG) do {                              \
  r = mfma16(W3[0], F0, r); z = mfma16(W3[1], F0, z); g = mfma16(W3[2], F0, QG); \
} while (0)

// Lockstep barrier (decoder only): drain LDS ops, then raw s_barrier.
#define SYNC() do {                                         \
  asm volatile("s_waitcnt lgkmcnt(0)" ::: "memory");        \
  __builtin_amdgcn_s_barrier();                             \
  asm volatile("" ::: "memory");                            \
} while (0)

// Encoder sync: sum-counter polls (pure spin, no s_sleep — detection = one LDS
// round-trip). ctrA/ctrB = 4 x (group's completed steps). Monotone thresholds,
// A leads / B chases -> no circular wait. DS ops of one wave execute in order:
// the ds_add publish cannot pass the preceding h/x ds_writes.
__device__ __forceinline__ void pollge(const volatile uint* p, uint need) {
  while (*p < need) { }
  asm volatile("" ::: "memory");
}
#define PUBLISH() do { asm volatile("" ::: "memory"); if (lane == 0) atomicAdd(myctr, 1u); } while (0)

__global__ void __launch_bounds__(512, 2)
gru_persist(const float* __restrict__ x,
            const float* __restrict__ eWih0, const float* __restrict__ eWhh0,
            const float* __restrict__ ebih0, const float* __restrict__ ebhh0,
            const float* __restrict__ eWih1, const float* __restrict__ eWhh1,
            const float* __restrict__ ebih1, const float* __restrict__ ebhh1,
            const float* __restrict__ dWih0, const float* __restrict__ dWhh0,
            const float* __restrict__ dbih0, const float* __restrict__ dbhh0,
            const float* __restrict__ dWih1, const float* __restrict__ dWhh1,
            const float* __restrict__ dbih1, const float* __restrict__ dbhh1,
            const float* __restrict__ outW, const float* __restrict__ outB,
            float* __restrict__ out)
{
  __shared__ __align__(16) _Float16 s0[NSL][16][RS0];
  __shared__ __align__(16) _Float16 s1[NSL][16][RS1];
  __shared__ __align__(16) uint prog[16];   // prog[0]=ctrA, prog[8]=ctrB

  const int tid  = threadIdx.x;
  const bool isA = tid < 256;          // A = layer0 waves, B = layer1 waves
  const int wvL  = (tid >> 6) & 3;
  const int lane = tid & 63;
  const int c    = lane & 15;
  const int q    = lane >> 4;
  const int ub   = wvL * 16 + q * 4;   // base h-col of this lane's 4 nonlin elems
  const long base = (long)blockIdx.x * GROWS;

  const volatile uint* vA = (const volatile uint*)&prog[0];
  const volatile uint* vB = (const volatile uint*)&prog[8];
  uint* myctr = (uint*)&prog[isA ? 0 : 8];

  for (int i = tid; i < NSL * 16 * RS0; i += 512) ((uint16_t*)s0)[i] = 0;
  for (int i = tid; i < NSL * 16 * RS1; i += 512) ((uint16_t*)s1)[i] = 0;
  if (tid < 16) prog[tid] = 0;
  if (tid < GROWS * NIN) {  // x(0) -> s0[0]
    int m = tid / 6, i2 = tid - m * 6;
    s0[0][m][64 + i2] = (_Float16)x[(base + m) * (TSEQ * NIN) + i2];
  }

  // encoder + decoder weights ALL register-resident from the start
  half8 W1[3][2], W2[3][2];    // encoder: A: Whh0 / (W2 unused by A) | B: Wih1 / Whh1
  half8 W2e[3];                // A: Wih0 fold, first K-half only
  half8 W1d[3][2], W2d[3][2];  // decoder: A: Whh0d / rank-1 fold | B: Wih1d / Whh1d
  float hr[4] = {0, 0, 0, 0};
  const float SC[3] = {L2E, L2E, 2.0f * L2E};   // r, z, n row scales (fold exp2 args)

  auto loadW64 = [&](const float* W, half8 (&D)[3][2]) {
    #pragma unroll
    for (int s = 0; s < 3; s++) {
      const int n = (s * 4 + wvL) * 16 + c;
      #pragma unroll
      for (int kt = 0; kt < 2; kt++) {
        const int k0 = kt * 32 + q * 8;
        #pragma unroll
        for (int j = 0; j < 8; j++) D[s][kt][j] = (_Float16)(SC[s] * W[n * 64 + k0 + j]);
      }
    }
  };

  // Packed nonlin (R9): shared-rcp sigmoid pair, shared-rcp tanh pair, b64 store.
  auto NLIN = [&](const floatx4 R, const floatx4 Z, const floatx4 GIN, const floatx4 GHN,
                  _Float16* dst) {
    half4v hv;
    #pragma unroll
    for (int pr = 0; pr < 2; pr++) {
      const int e = pr * 2;
      float2v er, ez;
      er.x = __builtin_amdgcn_exp2f(-R[e]);   er.y = __builtin_amdgcn_exp2f(-R[e + 1]);
      ez.x = __builtin_amdgcn_exp2f(-Z[e]);   ez.y = __builtin_amdgcn_exp2f(-Z[e + 1]);
      const float2v Dr = 1.0f + er, Dz = 1.0f + ez;
      const float2v P  = Dr * Dz;
      float2v rp;
      rp.x = __builtin_amdgcn_rcpf(P.x);      rp.y = __builtin_amdgcn_rcpf(P.y);
      const float2v gr = rp * Dz, gz = rp * Dr;
      const float2v gin = {GIN[e], GIN[e + 1]}, ghn = {GHN[e], GHN[e + 1]};
      const float2v vn = gin + gr * ghn;
      float2v en;
      en.x = __builtin_amdgcn_exp2f(-vn.x);   en.y = __builtin_amdgcn_exp2f(-vn.y);
      const float2v Dn = 1.0f + en;
      const float rpn = __builtin_amdgcn_rcpf(Dn.x * Dn.y);   // shared tanh rcp
      const float2v dsw = {Dn.y, Dn.x};
      const float2v nn = (2.0f * rpn) * dsw - 1.0f;
      const float2v hold = {hr[e], hr[e + 1]};
      const float2v hn = nn + gz * (hold - nn);
      hr[e] = hn.x; hr[e + 1] = hn.y;
      hv[e] = (_Float16)hn.x; hv[e + 1] = (_Float16)hn.y;
    }
    *(half4v*)dst = hv;
  };

  const float ob = outB[0];
  floatx4 QR, QZ, Q3, Q4;        // encoder consts (per-elem: gate = ub + r)
  floatx4 DRv, DZv, D3v, D4v;    // decoder steady consts
  floatx4 TRv, TZv, T3v, T4v;    // A decoder first-step consts
  float wk[2][8];                // B: head weights
  if (isA) {
    loadW64(eWhh0, W1);
    #pragma unroll
    for (int s = 0; s < 3; s++) {
      const int n = (s * 4 + wvL) * 16 + c;
      #pragma unroll
      for (int j = 0; j < 8; j++) {
        float v = (q == 0 && j < NIN) ? SC[s] * eWih0[n * NIN + j] : 0.0f;
        W2e[s][j] = (_Float16)v;
      }
    }
    loadW64(dWhh0, W1d);
    #pragma unroll
    for (int s = 0; s < 3; s++) {   // W2d = rank-1 head fold: SC[s] * dWih0[n] * outW[k]
      const int n = (s * 4 + wvL) * 16 + c;
      const float wd = SC[s] * dWih0[n];
      #pragma unroll
      for (int kt = 0; kt < 2; kt++) {
        const int k0 = kt * 32 + q * 8;
        #pragma unroll
        for (int j = 0; j < 8; j++) W2d[s][kt][j] = (_Float16)(wd * outW[k0 + j]);
      }
    }
    #pragma unroll
    for (int r = 0; r < 4; r++) {
      const int g = ub + r;
      QR[r] = L2E * (ebih0[g] + ebhh0[g]);
      QZ[r] = L2E * (ebih0[64 + g] + ebhh0[64 + g]);
      Q3[r] = 2.0f * L2E * ebhh0[128 + g];   // gh const
      Q4[r] = 2.0f * L2E * ebih0[128 + g];   // gi const
      TRv[r] = L2E * (dbih0[g] + dbhh0[g]);
      TZv[r] = L2E * (dbih0[64 + g] + dbhh0[64 + g]);
      T3v[r] = 2.0f * L2E * dbhh0[128 + g];
      T4v[r] = 2.0f * L2E * dbih0[128 + g];
      DRv[r] = TRv[r] + L2E * (dWih0[g] * ob);
      DZv[r] = TZv[r] + L2E * (dWih0[64 + g] * ob);
      D3v[r] = T3v[r];
      D4v[r] = T4v[r] + 2.0f * L2E * (dWih0[128 + g] * ob);
    }
  } else {
    loadW64(eWih1, W1); loadW64(eWhh1, W2);
    loadW64(dWih1, W1d); loadW64(dWhh1, W2d);
    #pragma unroll
    for (int r = 0; r < 4; r++) {
      const int g = ub + r;
      QR[r] = L2E * (ebih1[g] + ebhh1[g]);
      QZ[r] = L2E * (ebih1[64 + g] + ebhh1[64 + g]);
      Q3[r] = 2.0f * L2E * ebih1[128 + g];   // gi const
      Q4[r] = 2.0f * L2E * ebhh1[128 + g];   // gh const
      DRv[r] = L2E * (dbih1[g] + dbhh1[g]);
      DZv[r] = L2E * (dbih1[64 + g] + dbhh1[64 + g]);
      D3v[r] = 2.0f * L2E * dbih1[128 + g];
      D4v[r] = 2.0f * L2E * dbhh1[128 + g];
    }
    #pragma unroll
    for (int kt = 0; kt < 2; kt++)
      #pragma unroll
      for (int j = 0; j < 8; j++) wk[kt][j] = outW[kt * 32 + q * 8 + j];
  }
  __syncthreads();   // counters zeroed + x(0) staged; encoder runs on polls

  // ===== ENCODER: poll-synced, A free-runs up to 3 ahead of B =====
  // A-step i: needs ctrA>=4i (peers' h0(i-1)), ctrB>=4(i-3) (WAR: B-iter i-4
  //           consumed slot (i+1)&3). Produces h0(i), x(i+1) -> s0[(i+1)&3].
  // B-iter j: needs ctrB>=4j (peers' h1(j-1)), ctrA>=4(j+1) (h0(j) ready).
  //           Produces h1(j) -> s1[(j+1)&3].
  // DECODER: barrier lockstep, 360 SYNCs per side (A: 1+358+1, B: 1+1+358).
  if (isA) {
    // ---- x prefetch, spread over ALL 4 A-waves (lanes 0..23, 1 slot, depth 2)
    const bool doX = (lane < 24);
    const float *px0 = nullptr;
    int xo0 = 0;
    float xa0 = 0.f, xb0 = 0.f;
    if (doX) {
      int s_ = wvL * 24 + lane;                 // 96 slots = 16 rows x 6 features
      int m0 = s_ / 6, i0 = s_ - m0 * 6;
      px0 = x + (base + m0) * (TSEQ * NIN) + i0;
      xo0 = m0 * RS0 + 64 + i0;
      xa0 = px0[NIN];       // x(1)
      xb0 = px0[2 * NIN];   // x(2)
    }
    for (int k = 0; k < TSEQ; k += 4) {
      #pragma unroll
      for (int h4 = 0; h4 < 4; h4++) {
        const int i_ = k + h4, p = h4, pn = (h4 + 1) & 3;
        pollge(vA, 4u * (uint)i_);                       // peers done step i_-1
        const half8 a0 = ldh8(&s0[p][c][q * 8]);
        const half8 a1 = ldh8(&s0[p][c][32 + q * 8]);
        const half8 xf = ldh8(&s0[p][c][64 + q * 8]);
        floatx4 aR = QR, aZ = QZ, a3 = Q3, a4 = Q4;
        {
          floatx4 tR, tZ, tG;
          PASS2_I3(a0, a1, tR, tZ, tG, W1, aR, aZ, a3);  // Whh0.h0 -> gh
          aR = tR; aZ = tZ; a3 = tG;
        }
        PASS1_I1(xf, aR, aZ, a4, W2e, a4);               // Wih0.x  -> gi
        pollge(vB, i_ > 3 ? 4u * (uint)(i_ - 3) : 0u);   // WAR: B-iter i_-4 done
        if (doX && i_ + 1 < TSEQ) {
          ((_Float16*)s0[pn])[xo0] = (_Float16)xa0;
          xa0 = xb0;
          if (i_ + 3 < TSEQ) xb0 = px0[(i_ + 3) * NIN];
        }
        NLIN(aR, aZ, a4, a3, &s0[pn][c][ub]);            // h0(i_) -> s0[pn]
        PUBLISH();
      }
    }
    // ---- decoder peel A(0): prev = 0 -> base biases; h0_dec(0) -> s0[1] ----
    pollge(vA, 4u * (uint)TSEQ);        // all A-waves done step 255
    pollge(vB, 4u * (uint)(TSEQ - 3));  // WAR on s0[1]: B-iter 252 consumed it
    {
      const half8 a0 = ldh8(&s0[0][c][q * 8]);
      const half8 a1 = ldh8(&s0[0][c][32 + q * 8]);
      floatx4 aR, aZ, a3;
      PASS2_I3(a0, a1, aR, aZ, a3, W1d, TRv, TZv, T3v);
      NLIN(aR, aZ, T4v, a3, &s0[1][c][ub]);
      SYNC();   // bar0: joins B after its iter 255; h0_dec(0) visible
    }
    // ---- decoder steady: d = 1..179 (i_ = TSEQ+d), 2 barriers per step ----
    for (int i_ = TSEQ + 1; i_ < TSEQ + TDEC; i_++) {
      const int p = i_ & 3, pn = (i_ + 1) & 3;
      // prepass (overlaps B finishing d-1): Whh0d.h0_dec(d-1)
      const half8 a0 = ldh8(&s0[p][c][q * 8]);
      const half8 a1 = ldh8(&s0[p][c][32 + q * 8]);
      floatx4 aR, aZ, a3, a4;
      PASS2_I3(a0, a1, aR, aZ, a3, W1d, DRv, DZv, D3v);
      SYNC();                                          // B(d-1) done -> s1[p]
      const half8 b0 = ldh8(&s1[p][c][q * 8]);         // rank-1 head fold: W'.h1(d-1)
      const half8 b1 = ldh8(&s1[p][c][32 + q * 8]);
      PASS2_A2I1(b0, b1, aR, aZ, a4, W2d, D4v);
      NLIN(aR, aZ, a4, a3, &s0[pn][c][ub]);
      SYNC();                                          // A(d) done -> s0[pn]
    }
    SYNC();   // match B's barrier after its last finish (B(179))
  } else {
    // =========================== group B: layer 1 ===========================
    // ---- encoder: uniform j = 0..255, iter j produces h1(j) ----
    for (int k = 0; k < TSEQ; k += 4) {
      #pragma unroll
      for (int h4 = 0; h4 < 4; h4++) {
        const int j_ = k + h4, p = h4, pn = (h4 + 1) & 3;
        pollge(vB, 4u * (uint)j_);                      // peers done iter j_-1
        const half8 f0 = ldh8(&s1[p][c][q * 8]);        // h1(j_-1)
        const half8 f1 = ldh8(&s1[p][c][32 + q * 8]);
        floatx4 aR, aZ, a3, a4;
        PASS2_I3(f0, f1, aR, aZ, a4, W2, QR, QZ, Q4);   // Whh1.h1 -> gh
        pollge(vA, 4u * (uint)(j_ + 1));                // h0(j_) ready
        const half8 g0 = ldh8(&s0[pn][c][q * 8]);       // h0(j_)
        const half8 g1 = ldh8(&s0[pn][c][32 + q * 8]);
        PASS2_A2I1(g0, g1, aR, aZ, a3, W1, Q3);         // Wih1.h0 -> gi
        NLIN(aR, aZ, a3, a4, &s1[pn][c][ub]);           // h1(j_) -> s1[pn]
        PUBLISH();
      }
    }
    SYNC();   // bar0: joins A's peel; h1(255) [s1[0]] + h0_dec(0) [s0[1]] visible
    // ---- B(0): s1[0] = h1(255), s0[1] = h0_dec(0) -> s1[1] = h1_dec(0) ----
    {
      const half8 f0 = ldh8(&s1[0][c][q * 8]);
      const half8 f1 = ldh8(&s1[0][c][32 + q * 8]);
      floatx4 aR, aZ, a3, a4;
      PASS2_I3(f0, f1, aR, aZ, a4, W2d, DRv, DZv, D4v);
      const half8 g0 = ldh8(&s0[1][c][q * 8]);
      const half8 g1 = ldh8(&s0[1][c][32 + q * 8]);
      PASS2_A2I1(g0, g1, aR, aZ, a3, W1d, D3v);
      NLIN(aR, aZ, a3, a4, &s1[1][c][ub]);
      SYNC();   // bar1: h1_dec(0) visible
    }
    // ---- decoder steady: d = 1..179 (i_ = TSEQ+d), 2 barriers per step ----
    for (int i_ = TSEQ + 1; i_ < TSEQ + TDEC; i_++) {
      const int p = i_ & 3, pn = (i_ + 1) & 3;
      // prepass (overlaps A finishing d): Whh1d.h1_dec(d-1), + head cv(d-1)
      const half8 f0 = ldh8(&s1[p][c][q * 8]);
      const half8 f1 = ldh8(&s1[p][c][32 + q * 8]);
      floatx4 aR, aZ, a3, a4;
      PASS2_I3(f0, f1, aR, aZ, a4, W2d, DRv, DZv, D4v);  // Whh1.h1 -> gh
      if (wvL == 0) {   // head: cv(d-1) from h1_dec(d-1) fragments (off critical path)
        float cv = 0.0f;
        #pragma unroll
        for (int j = 0; j < 8; j++) {
          cv = fmaf((float)f0[j], wk[0][j], cv);
          cv = fmaf((float)f1[j], wk[1][j], cv);
        }
        cv += __shfl_xor(cv, 16);
        cv += __shfl_xor(cv, 32);
        if (lane < 16) out[(base + lane) * TDEC + (i_ - TSEQ - 1)] = cv + ob;
      }
      SYNC();                                          // A(d) done -> s0[pn]
      const half8 g0 = ldh8(&s0[pn][c][q * 8]);
      const half8 g1 = ldh8(&s0[pn][c][32 + q * 8]);
      PASS2_A2I1(g0, g1, aR, aZ, a3, W1d, D3v);        // Wih1.h0 -> gi
      NLIN(aR, aZ, a3, a4, &s1[pn][c][ub]);
      SYNC();                                          // B(d) done -> s1[pn]
    }
    // final head value: cv(179) from h1_dec(179) in s1[(436)&3 = 0]
    if (wvL == 0) {
      const half8 f0 = ldh8(&s1[0][c][q * 8]);
      const half8 f1 = ldh8(&s1[0][c][32 + q * 8]);
      float cv = 0.0f;
      #pragma unroll
      for (int j = 0; j < 8; j++) {
        cv = fmaf((float)f0[j], wk[0][j], cv);
        cv = fmaf((float)f1[j], wk[1][j], cv);
      }
      cv += __shfl_xor(cv, 16);
      cv += __shfl_xor(cv, 32);
      if (lane < 16) out[(base + lane) * TDEC + (TDEC - 1)] = cv + ob;
    }
  }
}

extern "C" void kernel_launch(void* const* d_in, const int* in_sizes, int n_in,
                              void* d_out, int out_size, void* d_ws, size_t ws_size,
                              hipStream_t stream) {
  (void)in_sizes; (void)n_in; (void)d_ws; (void)ws_size; (void)out_size;
  const float* x     = (const float*)d_in[0];
  const float* eWih0 = (const float*)d_in[1];
  const float* eWhh0 = (const float*)d_in[2];
  const float* ebih0 = (const float*)d_in[3];
  const float* ebhh0 = (const float*)d_in[4];
  const float* eWih1 = (const float*)d_in[5];
  const float* eWhh1 = (const float*)d_in[6];
  const float* ebih1 = (const float*)d_in[7];
  const float* ebhh1 = (const float*)d_in[8];
  const float* dWih0 = (const float*)d_in[9];
  const float* dWhh0 = (const float*)d_in[10];
  const float* dbih0 = (const float*)d_in[11];
  const float* dbhh0 = (const float*)d_in[12];
  const float* dWih1 = (const float*)d_in[13];
  const float* dWhh1 = (const float*)d_in[14];
  const float* dbih1 = (const float*)d_in[15];
  const float* dbhh1 = (const float*)d_in[16];
  const float* outW  = (const float*)d_in[17];
  const float* outB  = (const float*)d_in[18];
  hipLaunchKernelGGL(gru_persist, dim3(NBLK), dim3(512), 0, stream,
                     x, eWih0, eWhh0, ebih0, ebhh0, eWih1, eWhh1, ebih1, ebhh1,
                     dWih0, dWhh0, dbih0, dbhh0, dWih1, dWhh1, dbih1, dbhh1,
                     outW, outB, (float*)d_out);
}

// Round 11
// 343.175 us; speedup vs baseline: 1.0282x; 1.0282x over previous
//
#include <hip/hip_runtime.h>
#include <cstdint>

typedef _Float16 half8 __attribute__((ext_vector_type(8)));
typedef _Float16 half4v __attribute__((ext_vector_type(4)));
typedef __attribute__((ext_vector_type(4))) float floatx4;
typedef __attribute__((ext_vector_type(2))) float float2v;

#define TSEQ 256
#define TDEC 180
#define NIN  6
#define GROWS 16
#define NBLK (4096 / GROWS)
#define NSL 4     // state buffer depth: h(j) lives in slot (j+1)&3
#define RS0 104   // s0 row stride (halfs): cols 0..63 h0, 64..95 x|0, 96..103 pad
#define RS1 72    // s1 row stride
#define L2E 1.4426950408889634f

__device__ __forceinline__ floatx4 mfma16(half8 a, half8 b, floatx4 c) {
  return __builtin_amdgcn_mfma_f32_16x16x32_f16(a, b, c, 0, 0, 0);
}

__device__ __forceinline__ half8 ldh8(const _Float16* p) { return *(const half8*)p; }

// ---- OPERAND-SWAPPED MFMA passes: gates^T = W_tile . h^T (bit-identical sums;
// C layout (gate row, batch col) -> lane's 4 outputs are 4 consecutive h-cols
// of one batch row -> single ds_write_b64).
#define PASS2_I3(F0, F1, r, z, g, W, QR, QZ, QG) do {                   \
  r = mfma16(W[0][0], F0, QR); z = mfma16(W[1][0], F0, QZ); g = mfma16(W[2][0], F0, QG); \
  r = mfma16(W[0][1], F1, r);  z = mfma16(W[1][1], F1, z);  g = mfma16(W[2][1], F1, g);  \
} while (0)

#define PASS2_A2I1(F0, F1, r, z, g, W, QG) do {                         \
  r = mfma16(W[0][0], F0, r); z = mfma16(W[1][0], F0, z); g = mfma16(W[2][0], F0, QG); \
  r = mfma16(W[0][1], F1, r); z = mfma16(W[1][1], F1, z); g = mfma16(W[2][1], F1, g);  \
} while (0)

// layer0 x-pass: only the first K-half is nonzero (x has 6 features) -> 1-D W.
#define PASS1_I1(F0, r, z, g, W3, QG) do {                              \
  r = mfma16(W3[0], F0, r); z = mfma16(W3[1], F0, z); g = mfma16(W3[2], F0, QG); \
} while (0)

// Lockstep barrier: drain this wave's LDS ops (writes become visible), then
// raw s_barrier. Deliberately NO vmcnt drain so global prefetch loads stay in
// flight across barriers. Memory clobbers pin LDS ops on each side.
#define SYNC() do {                                         \
  asm volatile("s_waitcnt lgkmcnt(0)" ::: "memory");        \
  __builtin_amdgcn_s_barrier();                             \
  asm volatile("" ::: "memory");                            \
} while (0)

__global__ void __launch_bounds__(512, 2)
gru_persist(const float* __restrict__ x,
            const float* __restrict__ eWih0, const float* __restrict__ eWhh0,
            const float* __restrict__ ebih0, const float* __restrict__ ebhh0,
            const float* __restrict__ eWih1, const float* __restrict__ eWhh1,
            const float* __restrict__ ebih1, const float* __restrict__ ebhh1,
            const float* __restrict__ dWih0, const float* __restrict__ dWhh0,
            const float* __restrict__ dbih0, const float* __restrict__ dbhh0,
            const float* __restrict__ dWih1, const float* __restrict__ dWhh1,
            const float* __restrict__ dbih1, const float* __restrict__ dbhh1,
            const float* __restrict__ outW, const float* __restrict__ outB,
            float* __restrict__ out)
{
  __shared__ __align__(16) _Float16 s0[NSL][16][RS0];
  __shared__ __align__(16) _Float16 s1[NSL][16][RS1];
  __shared__ __align__(16) float cvpart[4][16];   // per-B-wave partial of outW.h1(d)

  const int tid  = threadIdx.x;
  const bool isA = tid < 256;          // A = layer0 waves, B = layer1 waves
  const int wvL  = (tid >> 6) & 3;
  const int lane = tid & 63;
  const int c    = lane & 15;
  const int q    = lane >> 4;
  const int ub   = wvL * 16 + q * 4;   // base h-col of this lane's 4 nonlin elems
  const long base = (long)blockIdx.x * GROWS;

  for (int i = tid; i < NSL * 16 * RS0; i += 512) ((uint16_t*)s0)[i] = 0;
  for (int i = tid; i < NSL * 16 * RS1; i += 512) ((uint16_t*)s1)[i] = 0;
  if (tid < GROWS * NIN) {  // x(0) -> s0[0]
    int m = tid / 6, i2 = tid - m * 6;
    s0[0][m][64 + i2] = (_Float16)x[(base + m) * (TSEQ * NIN) + i2];
  }

  // register-resident weights (A's decoder rank-1 head fold is now SCALARIZED:
  // cv = outW.h1 computed once by B per step, A applies a 12-FMA rank-1 update
  // instead of 6 MFMAs)
  half8 W1[3][2], W2[3][2];    // encoder: A: Whh0 / (W2 unused by A) | B: Wih1 / Whh1
  half8 W2e[3];                // A: Wih0 fold, first K-half only
  half8 W1d[3][2], W2d[3][2];  // decoder: A: Whh0d / (W2d unused by A) | B: Wih1d / Whh1d
  float hr[4] = {0, 0, 0, 0};
  const float SC[3] = {L2E, L2E, 2.0f * L2E};   // r, z, n row scales (fold exp2 args)

  auto loadW64 = [&](const float* W, half8 (&D)[3][2]) {
    #pragma unroll
    for (int s = 0; s < 3; s++) {
      const int n = (s * 4 + wvL) * 16 + c;
      #pragma unroll
      for (int kt = 0; kt < 2; kt++) {
        const int k0 = kt * 32 + q * 8;
        #pragma unroll
        for (int j = 0; j < 8; j++) D[s][kt][j] = (_Float16)(SC[s] * W[n * 64 + k0 + j]);
      }
    }
  };

  // Packed nonlin (R9): shared-rcp sigmoid pair, shared-rcp tanh pair, b64 store.
  auto NLIN = [&](const floatx4 R, const floatx4 Z, const floatx4 GIN, const floatx4 GHN,
                  _Float16* dst) {
    half4v hv;
    #pragma unroll
    for (int pr = 0; pr < 2; pr++) {
      const int e = pr * 2;
      float2v er, ez;
      er.x = __builtin_amdgcn_exp2f(-R[e]);   er.y = __builtin_amdgcn_exp2f(-R[e + 1]);
      ez.x = __builtin_amdgcn_exp2f(-Z[e]);   ez.y = __builtin_amdgcn_exp2f(-Z[e + 1]);
      const float2v Dr = 1.0f + er, Dz = 1.0f + ez;
      const float2v P  = Dr * Dz;
      float2v rp;
      rp.x = __builtin_amdgcn_rcpf(P.x);      rp.y = __builtin_amdgcn_rcpf(P.y);
      const float2v gr = rp * Dz, gz = rp * Dr;
      const float2v gin = {GIN[e], GIN[e + 1]}, ghn = {GHN[e], GHN[e + 1]};
      const float2v vn = gin + gr * ghn;
      float2v en;
      en.x = __builtin_amdgcn_exp2f(-vn.x);   en.y = __builtin_amdgcn_exp2f(-vn.y);
      const float2v Dn = 1.0f + en;
      const float rpn = __builtin_amdgcn_rcpf(Dn.x * Dn.y);   // shared tanh rcp
      const float2v dsw = {Dn.y, Dn.x};
      const float2v nn = (2.0f * rpn) * dsw - 1.0f;
      const float2v hold = {hr[e], hr[e + 1]};
      const float2v hn = nn + gz * (hold - nn);
      hr[e] = hn.x; hr[e + 1] = hn.y;
      hv[e] = (_Float16)hn.x; hv[e + 1] = (_Float16)hn.y;
    }
    *(half4v*)dst = hv;
  };

  const float ob = outB[0];
  floatx4 QR, QZ, Q3, Q4;        // encoder consts (per-elem: gate = ub + r)
  floatx4 DRv, DZv, D3v, D4v;    // decoder steady consts
  floatx4 TRv, TZv, T3v, T4v;    // A decoder first-step consts
  floatx4 cfR, cfZ, cfN;         // A: rank-1 cv fold coefficients
  floatx4 wkv;                   // B: head weights outW[ub+r]
  if (isA) {
    loadW64(eWhh0, W1);
    #pragma unroll
    for (int s = 0; s < 3; s++) {
      const int n = (s * 4 + wvL) * 16 + c;
      #pragma unroll
      for (int j = 0; j < 8; j++) {
        float v = (q == 0 && j < NIN) ? SC[s] * eWih0[n * NIN + j] : 0.0f;
        W2e[s][j] = (_Float16)v;
      }
    }
    loadW64(dWhh0, W1d);
    #pragma unroll
    for (int r = 0; r < 4; r++) {
      const int g = ub + r;
      QR[r] = L2E * (ebih0[g] + ebhh0[g]);
      QZ[r] = L2E * (ebih0[64 + g] + ebhh0[64 + g]);
      Q3[r] = 2.0f * L2E * ebhh0[128 + g];   // gh const
      Q4[r] = 2.0f * L2E * ebih0[128 + g];   // gi const
      TRv[r] = L2E * (dbih0[g] + dbhh0[g]);
      TZv[r] = L2E * (dbih0[64 + g] + dbhh0[64 + g]);
      T3v[r] = 2.0f * L2E * dbhh0[128 + g];
      T4v[r] = 2.0f * L2E * dbih0[128 + g];
      DRv[r] = TRv[r] + L2E * (dWih0[g] * ob);
      DZv[r] = TZv[r] + L2E * (dWih0[64 + g] * ob);
      D3v[r] = T3v[r];
      D4v[r] = T4v[r] + 2.0f * L2E * (dWih0[128 + g] * ob);
      cfR[r] = L2E * dWih0[g];               // rank-1 cv fold (x cvb)
      cfZ[r] = L2E * dWih0[64 + g];
      cfN[r] = 2.0f * L2E * dWih0[128 + g];
    }
  } else {
    loadW64(eWih1, W1); loadW64(eWhh1, W2);
    loadW64(dWih1, W1d); loadW64(dWhh1, W2d);
    #pragma unroll
    for (int r = 0; r < 4; r++) {
      const int g = ub + r;
      QR[r] = L2E * (ebih1[g] + ebhh1[g]);
      QZ[r] = L2E * (ebih1[64 + g] + ebhh1[64 + g]);
      Q3[r] = 2.0f * L2E * ebih1[128 + g];   // gi const
      Q4[r] = 2.0f * L2E * ebhh1[128 + g];   // gh const
      DRv[r] = L2E * (dbih1[g] + dbhh1[g]);
      DZv[r] = L2E * (dbih1[64 + g] + dbhh1[64 + g]);
      D3v[r] = 2.0f * L2E * dbih1[128 + g];
      D4v[r] = 2.0f * L2E * dbhh1[128 + g];
      wkv[r] = outW[g];
    }
  }
  __syncthreads();   // everything after runs on the lockstep barrier schedule

  // Barrier schedule (both sides execute exactly 616 SYNCs):
  //   encoder: 256 iters (1 SYNC each) + 1 tail iter (A: decoder peel, B: enc step 255)
  //   decoder: B(0) window (1 SYNC), then 179 iters x 2 SYNCs; A adds 1 trailing SYNC.
  if (isA) {
    // ---- x prefetch, spread over ALL 4 A-waves (lanes 0..23, 1 slot each, depth 2)
    const bool doX = (lane < 24);
    const float *px0 = nullptr;
    int xo0 = 0;
    float xa0 = 0.f, xb0 = 0.f;   // (xa=next-to-write, xb=following)
    if (doX) {
      int s_ = wvL * 24 + lane;                 // 96 slots = 16 rows x 6 features
      int m0 = s_ / 6, i0 = s_ - m0 * 6;
      px0 = x + (base + m0) * (TSEQ * NIN) + i0;
      xo0 = m0 * RS0 + 64 + i0;
      xa0 = px0[NIN];       // x(1)
      xb0 = px0[2 * NIN];   // x(2)
    }
    // ================= encoder: iteration k computes h0_out(k) =================
    for (int k = 0; k < TSEQ; k += 4) {
      #pragma unroll
      for (int h4 = 0; h4 < 4; h4++) {
        const int i_ = k + h4, p = h4, pn = (h4 + 1) & 3;
        const half8 a0 = ldh8(&s0[p][c][q * 8]);
        const half8 a1 = ldh8(&s0[p][c][32 + q * 8]);
        const half8 xf = ldh8(&s0[p][c][64 + q * 8]);
        floatx4 aR = QR, aZ = QZ, a3 = Q3, a4 = Q4;
        {
          floatx4 tR, tZ, tG;
          PASS2_I3(a0, a1, tR, tZ, tG, W1, aR, aZ, a3);  // Whh0.h0 -> gh
          aR = tR; aZ = tZ; a3 = tG;
        }
        PASS1_I1(xf, aR, aZ, a4, W2e, a4);               // Wih0.x  -> gi
        if (doX && i_ + 1 < TSEQ) {
          ((_Float16*)s0[pn])[xo0] = (_Float16)xa0;
          xa0 = xb0;
          if (i_ + 3 < TSEQ) xb0 = px0[(i_ + 3) * NIN];
        }
        NLIN(aR, aZ, a4, a3, &s0[pn][c][ub]);            // nn = tanh(gi_n + gr*gh_n)
        SYNC();
      }
    }
    // ---- tail iteration (k=TSEQ): decoder peel A(0), prev = 0 -> base biases ----
    {
      const half8 a0 = ldh8(&s0[0][c][q * 8]);
      const half8 a1 = ldh8(&s0[0][c][32 + q * 8]);
      floatx4 aR, aZ, a3;
      PASS2_I3(a0, a1, aR, aZ, a3, W1d, TRv, TZv, T3v);
      NLIN(aR, aZ, T4v, a3, &s0[1][c][ub]);
      SYNC();   // bar0: h0_dec(0) visible; B(0) runs in the next window
    }
    // ---- decoder steady: d = 1..179 (i_ = TSEQ+d), 2 barriers per step ----
    for (int i_ = TSEQ + 1; i_ < TSEQ + TDEC; i_++) {
      const int p = i_ & 3, pn = (i_ + 1) & 3;
      // prepass (overlaps B finishing d-1): Whh0d.h0_dec(d-1)
      const half8 a0 = ldh8(&s0[p][c][q * 8]);
      const half8 a1 = ldh8(&s0[p][c][32 + q * 8]);
      floatx4 aR, aZ, a3, a4;
      PASS2_I3(a0, a1, aR, aZ, a3, W1d, DRv, DZv, D3v);
      SYNC();                                          // B(d-1) done -> cvpart = cv(d-1)
      // rank-1 head fold via scalar cv (replaces 6 MFMAs on W2d):
      const float cvf = cvpart[0][c] + cvpart[1][c] + cvpart[2][c] + cvpart[3][c];
      #pragma unroll
      for (int r = 0; r < 4; r++) {
        a4[r] = D4v[r] + cfN[r] * cvf;
        aR[r] = aR[r] + cfR[r] * cvf;
        aZ[r] = aZ[r] + cfZ[r] * cvf;
      }
      NLIN(aR, aZ, a4, a3, &s0[pn][c][ub]);
      SYNC();                                          // A(d) done -> s0[pn]
    }
    SYNC();   // match B's barrier after its last finish (B(179))
  } else {
    // =========================== group B: layer 1 ===========================
    // ============ encoder: iteration kk computes h1_out(kk-1), kk>=1 ============
    for (int k = 0; k < TSEQ; k += 4) {
      #pragma unroll
      for (int h4 = 0; h4 < 4; h4++) {
        const int kk = k + h4;
        if (kk > 0) {
          const int p = (h4 + 3) & 3, pn = h4;         // read s1[(kk-1)&3], s0[kk&3]
          const half8 f0 = ldh8(&s1[p][c][q * 8]);
          const half8 f1 = ldh8(&s1[p][c][32 + q * 8]);
          floatx4 aR, aZ, a3, a4;
          PASS2_I3(f0, f1, aR, aZ, a4, W2, QR, QZ, Q4);  // Whh1.h1 -> gh
          const half8 g0 = ldh8(&s0[pn][c][q * 8]);      // h0_out(kk-1), from prev window
          const half8 g1 = ldh8(&s0[pn][c][32 + q * 8]);
          PASS2_A2I1(g0, g1, aR, aZ, a3, W1, Q3);        // Wih1.h0 -> gi
          NLIN(aR, aZ, a3, a4, &s1[pn][c][ub]);          // nn = tanh(gi_n + gr*gh_n)
        }
        SYNC();
      }
    }
    // ---- tail iteration (kk=TSEQ): encoder step i_=255: s1[3], s0[0] -> s1[0] ----
    {
      const half8 f0 = ldh8(&s1[3][c][q * 8]);
      const half8 f1 = ldh8(&s1[3][c][32 + q * 8]);
      floatx4 aR, aZ, a3, a4;
      PASS2_I3(f0, f1, aR, aZ, a4, W2, QR, QZ, Q4);
      const half8 g0 = ldh8(&s0[0][c][q * 8]);
      const half8 g1 = ldh8(&s0[0][c][32 + q * 8]);
      PASS2_A2I1(g0, g1, aR, aZ, a3, W1, Q3);
      NLIN(aR, aZ, a3, a4, &s1[0][c][ub]);
      SYNC();   // bar0
    }
    // ---- B(0): s1[0] = h1_out(255), s0[1] = h0_dec(0) -> s1[1] = h1_dec(0) ----
    {
      const half8 f0 = ldh8(&s1[0][c][q * 8]);
      const half8 f1 = ldh8(&s1[0][c][32 + q * 8]);
      floatx4 aR, aZ, a3, a4;
      PASS2_I3(f0, f1, aR, aZ, a4, W2d, DRv, DZv, D4v);
      const half8 g0 = ldh8(&s0[1][c][q * 8]);
      const half8 g1 = ldh8(&s0[1][c][32 + q * 8]);
      PASS2_A2I1(g0, g1, aR, aZ, a3, W1d, D3v);
      NLIN(aR, aZ, a3, a4, &s1[1][c][ub]);
      // publish cv partials of h1_dec(0) for A's first steady finish
      {
        float cvp = hr[0] * wkv[0] + hr[1] * wkv[1] + hr[2] * wkv[2] + hr[3] * wkv[3];
        cvp += __shfl_xor(cvp, 16);
        cvp += __shfl_xor(cvp, 32);
        if (lane < 16) cvpart[wvL][lane] = cvp;
      }
      SYNC();   // bar1: h1_dec(0) + cvpart visible
    }
    // ---- decoder steady: d = 1..179 (i_ = TSEQ+d), 2 barriers per step ----
    for (int i_ = TSEQ + 1; i_ < TSEQ + TDEC; i_++) {
      const int p = i_ & 3, pn = (i_ + 1) & 3;
      // prepass (overlaps A finishing d): Whh1d.h1_dec(d-1), + head output cv(d-1)
      const half8 f0 = ldh8(&s1[p][c][q * 8]);
      const half8 f1 = ldh8(&s1[p][c][32 + q * 8]);
      floatx4 aR, aZ, a3, a4;
      PASS2_I3(f0, f1, aR, aZ, a4, W2d, DRv, DZv, D4v);  // Whh1.h1 -> gh
      if (wvL == 0 && lane < 16) {   // head: cv(d-1) from cvpart (off critical path)
        const float cv = cvpart[0][lane] + cvpart[1][lane]
                       + cvpart[2][lane] + cvpart[3][lane];
        out[(base + lane) * TDEC + (i_ - TSEQ - 1)] = cv + ob;
      }
      SYNC();                                          // A(d) done -> s0[pn] = h0_dec(d)
      const half8 g0 = ldh8(&s0[pn][c][q * 8]);
      const half8 g1 = ldh8(&s0[pn][c][32 + q * 8]);
      PASS2_A2I1(g0, g1, aR, aZ, a3, W1d, D3v);        // Wih1.h0 -> gi
      NLIN(aR, aZ, a3, a4, &s1[pn][c][ub]);
      // publish cv partials of h1_dec(d) (f32 hr, pre-f16-rounding)
      {
        float cvp = hr[0] * wkv[0] + hr[1] * wkv[1] + hr[2] * wkv[2] + hr[3] * wkv[3];
        cvp += __shfl_xor(cvp, 16);
        cvp += __shfl_xor(cvp, 32);
        if (lane < 16) cvpart[wvL][lane] = cvp;
      }
      SYNC();                                          // B(d) done -> s1[pn] + cvpart
    }
    // final head value: cv(179) from cvpart of h1_dec(179)
    if (wvL == 0 && lane < 16) {
      const float cv = cvpart[0][lane] + cvpart[1][lane]
                     + cvpart[2][lane] + cvpart[3][lane];
      out[(base + lane) * TDEC + (TDEC - 1)] = cv + ob;
    }
  }
}

extern "C" void kernel_launch(void* const* d_in, const int* in_sizes, int n_in,
                              void* d_out, int out_size, void* d_ws, size_t ws_size,
                              hipStream_t stream) {
  (void)in_sizes; (void)n_in; (void)d_ws; (void)ws_size; (void)out_size;
  const float* x     = (const float*)d_in[0];
  const float* eWih0 = (const float*)d_in[1];
  const float* eWhh0 = (const float*)d_in[2];
  const float* ebih0 = (const float*)d_in[3];
  const float* ebhh0 = (const float*)d_in[4];
  const float* eWih1 = (const float*)d_in[5];
  const float* eWhh1 = (const float*)d_in[6];
  const float* ebih1 = (const float*)d_in[7];
  const float* ebhh1 = (const float*)d_in[8];
  const float* dWih0 = (const float*)d_in[9];
  const float* dWhh0 = (const float*)d_in[10];
  const float* dbih0 = (const float*)d_in[11];
  const float* dbhh0 = (const float*)d_in[12];
  const float* dWih1 = (const float*)d_in[13];
  const float* dWhh1 = (const float*)d_in[14];
  const float* dbih1 = (const float*)d_in[15];
  const float* dbhh1 = (const float*)d_in[16];
  const float* outW  = (const float*)d_in[17];
  const float* outB  = (const float*)d_in[18];
  hipLaunchKernelGGL(gru_persist, dim3(NBLK), dim3(512), 0, stream,
                     x, eWih0, eWhh0, ebih0, ebhh0, eWih1, eWhh1, ebih1, ebhh1,
                     dWih0, dWhh0, dbih0, dbhh0, dWih1, dWhh1, dbih1, dbhh1,
                     outW, outB, (float*)d_out);
}